// Round 5
// baseline (867.683 us; speedup 1.0000x reference)
//
#include <hip/hip_runtime.h>
#include <math.h>

#define CC 64
#define KK 20
#define DCH 32
#define LOG2E 1.4426950408889634f
#define LN2   0.6931471805599453f
#define LN2PI 1.8378770664093453f
#define BIGN  -1.0e9f

#if __has_builtin(__builtin_amdgcn_exp2f)
#define EXP2(x) __builtin_amdgcn_exp2f(x)
#else
#define EXP2(x) exp2f(x)
#endif
#if __has_builtin(__builtin_amdgcn_logf)
#define LOG2(x) __builtin_amdgcn_logf(x)
#else
#define LOG2(x) log2f(x)
#endif

__device__ __forceinline__ float rlane(float v, int l) {
  return __int_as_float(__builtin_amdgcn_readlane(__float_as_int(v), l));
}

template <int Ctrl, int OldBits>
__device__ __forceinline__ float dpp_mov(float x) {
  return __int_as_float(__builtin_amdgcn_update_dpp(
      OldBits, __float_as_int(x), Ctrl, 0xf, 0xf, false));
}

__device__ __forceinline__ float wave_max64(float x) {
  constexpr int NI = (int)0xff800000;  // -inf
  x = fmaxf(x, dpp_mov<0x111, NI>(x));
  x = fmaxf(x, dpp_mov<0x112, NI>(x));
  x = fmaxf(x, dpp_mov<0x114, NI>(x));
  x = fmaxf(x, dpp_mov<0x118, NI>(x));
  x = fmaxf(x, dpp_mov<0x142, NI>(x));
  x = fmaxf(x, dpp_mov<0x143, NI>(x));
  return __int_as_float(__builtin_amdgcn_readlane(__float_as_int(x), 63));
}

__device__ __forceinline__ float wave_sum64(float x) {
  x += dpp_mov<0x111, 0>(x);
  x += dpp_mov<0x112, 0>(x);
  x += dpp_mov<0x114, 0>(x);
  x += dpp_mov<0x118, 0>(x);
  x += dpp_mov<0x142, 0>(x);
  x += dpp_mov<0x143, 0>(x);
  return __int_as_float(__builtin_amdgcn_readlane(__float_as_int(x), 63));
}

// ---------------------------------------------------------------------------
// Setup (R3-proven)
// ---------------------------------------------------------------------------
__global__ void setup_kernel(const float* __restrict__ means,
                             const float* __restrict__ cov,
                             const float* __restrict__ tl,
                             const float* __restrict__ il,
                             const float* __restrict__ plr,
                             float* __restrict__ wmat,
                             float* __restrict__ invvar,
                             float* __restrict__ q2,
                             float* __restrict__ P_T,
                             float* __restrict__ init2,
                             float* __restrict__ len2,
                             int D) {
  __shared__ float red[256];
  int tid = threadIdx.x;
  for (int d = tid; d < D; d += 256) invvar[d] = 1.0f / cov[(size_t)d * D + d];
  float lp_ = 0.f;
  for (int d = tid; d < D; d += 256) lp_ += logf(cov[(size_t)d * D + d]);
  red[tid] = lp_;
  __syncthreads();
  for (int s = 128; s > 0; s >>= 1) {
    if (tid < s) red[tid] += red[tid + s];
    __syncthreads();
  }
  float logdet = red[0];
  __syncthreads();
  {
    int c = tid & 63, q = tid >> 6;
    int dq = D / 4;
    float m2p = 0.f;
    for (int d = q * dq; d < (q + 1) * dq; ++d) {
      float mu = means[c * D + d];
      m2p = fmaf(mu * mu, invvar[d], m2p);
    }
    red[tid] = m2p;
  }
  __syncthreads();
  for (int i = tid; i < CC * D; i += 256) wmat[i] = means[i] * invvar[i % D];
  if (tid < CC) {
    int c = tid;
    float m2 = red[c] + red[c + 64] + red[c + 128] + red[c + 192];
    q2[c] = -0.5f * LOG2E * (m2 + logdet + (float)D * LN2PI);
    int j = c;
    float mx = -1e30f;
    for (int i2 = 0; i2 < CC; ++i2) {
      float v = (i2 == j) ? BIGN : tl[i2 * CC + j];
      mx = fmaxf(mx, v);
    }
    float s = 0.f;
    for (int i2 = 0; i2 < CC; ++i2) {
      float v = (i2 == j) ? BIGN : tl[i2 * CC + j];
      s += expf(v - mx);
    }
    float inv = 1.f / s;
    for (int i2 = 0; i2 < CC; ++i2) {
      float v = (i2 == j) ? BIGN : tl[i2 * CC + j];
      P_T[j * CC + i2] = expf(v - mx) * inv;
    }
    float mi = -1e30f;
    for (int i2 = 0; i2 < CC; ++i2) mi = fmaxf(mi, il[i2]);
    float si = 0.f;
    for (int i2 = 0; i2 < CC; ++i2) si += expf(il[i2] - mi);
    init2[c] = LOG2E * (il[c] - (mi + logf(si)));
  }
  for (int i = tid; i < KK * CC; i += 256) {
    int k = i / CC, c = i % CC;
    float lr = plr[c];
    float lp = (float)(k + 1) * lr - expf(lr) - lgammaf((float)(k + 2));
    len2[i] = LOG2E * lp;
  }
}

// ---------------------------------------------------------------------------
// Emission (R3-proven version, unchanged)
// ---------------------------------------------------------------------------
__global__ __launch_bounds__(256) void emission_kernel(
    const float* __restrict__ feat,
    const float* __restrict__ wmat,
    const float* __restrict__ invvar,
    const float* __restrict__ q2,
    float* __restrict__ em2,
    int D) {
  __shared__ float xs[64][DCH + 1];
  __shared__ float wsh[64][DCH + 1];
  __shared__ float ivv[DCH];
  __shared__ float q2s[CC];
  int tid = threadIdx.x;
  size_t row0 = (size_t)blockIdx.x * 64;
  if (tid < CC) q2s[tid] = q2[tid];
  int tx = tid & 15, ty = tid >> 4;
  int r0 = ty * 4, c0 = tx * 4;
  int lr_ = tid >> 2;
  int lj  = (tid & 3) * 8;
  float acc00=0,acc01=0,acc02=0,acc03=0;
  float acc10=0,acc11=0,acc12=0,acc13=0;
  float acc20=0,acc21=0,acc22=0,acc23=0;
  float acc30=0,acc31=0,acc32=0,acc33=0;
  float x2a0=0,x2a1=0,x2a2=0,x2a3=0;
  for (int d0 = 0; d0 < D; d0 += DCH) {
    __syncthreads();
    {
      const float4* fx = (const float4*)(feat + (row0 + (size_t)lr_) * D + d0 + lj);
      float4 a = fx[0], b = fx[1];
      xs[lr_][lj+0]=a.x; xs[lr_][lj+1]=a.y; xs[lr_][lj+2]=a.z; xs[lr_][lj+3]=a.w;
      xs[lr_][lj+4]=b.x; xs[lr_][lj+5]=b.y; xs[lr_][lj+6]=b.z; xs[lr_][lj+7]=b.w;
      const float4* fw = (const float4*)(wmat + (size_t)lr_ * D + d0 + lj);
      float4 aw = fw[0], bw = fw[1];
      wsh[lr_][lj+0]=aw.x; wsh[lr_][lj+1]=aw.y; wsh[lr_][lj+2]=aw.z; wsh[lr_][lj+3]=aw.w;
      wsh[lr_][lj+4]=bw.x; wsh[lr_][lj+5]=bw.y; wsh[lr_][lj+6]=bw.z; wsh[lr_][lj+7]=bw.w;
      if (tid < DCH) ivv[tid] = invvar[d0 + tid];
    }
    __syncthreads();
    #pragma unroll
    for (int j = 0; j < DCH; ++j) {
      float iv = ivv[j];
      float xv0 = xs[r0+0][j], xv1 = xs[r0+1][j], xv2 = xs[r0+2][j], xv3 = xs[r0+3][j];
      float wv0 = wsh[c0+0][j], wv1 = wsh[c0+1][j], wv2 = wsh[c0+2][j], wv3 = wsh[c0+3][j];
      x2a0 = fmaf(xv0, xv0*iv, x2a0);
      x2a1 = fmaf(xv1, xv1*iv, x2a1);
      x2a2 = fmaf(xv2, xv2*iv, x2a2);
      x2a3 = fmaf(xv3, xv3*iv, x2a3);
      acc00 = fmaf(xv0, wv0, acc00); acc01 = fmaf(xv0, wv1, acc01);
      acc02 = fmaf(xv0, wv2, acc02); acc03 = fmaf(xv0, wv3, acc03);
      acc10 = fmaf(xv1, wv0, acc10); acc11 = fmaf(xv1, wv1, acc11);
      acc12 = fmaf(xv1, wv2, acc12); acc13 = fmaf(xv1, wv3, acc13);
      acc20 = fmaf(xv2, wv0, acc20); acc21 = fmaf(xv2, wv1, acc21);
      acc22 = fmaf(xv2, wv2, acc22); acc23 = fmaf(xv2, wv3, acc23);
      acc30 = fmaf(xv3, wv0, acc30); acc31 = fmaf(xv3, wv1, acc31);
      acc32 = fmaf(xv3, wv2, acc32); acc33 = fmaf(xv3, wv3, acc33);
    }
  }
  float qa = q2s[c0+0], qb = q2s[c0+1], qc = q2s[c0+2], qd = q2s[c0+3];
  {
    size_t row = row0 + r0 + 0; float h = 0.5f * x2a0; float4 o;
    o.x = LOG2E*(acc00-h)+qa; o.y = LOG2E*(acc01-h)+qb; o.z = LOG2E*(acc02-h)+qc; o.w = LOG2E*(acc03-h)+qd;
    *(float4*)&em2[row*CC + c0] = o;
  }
  {
    size_t row = row0 + r0 + 1; float h = 0.5f * x2a1; float4 o;
    o.x = LOG2E*(acc10-h)+qa; o.y = LOG2E*(acc11-h)+qb; o.z = LOG2E*(acc12-h)+qc; o.w = LOG2E*(acc13-h)+qd;
    *(float4*)&em2[row*CC + c0] = o;
  }
  {
    size_t row = row0 + r0 + 2; float h = 0.5f * x2a2; float4 o;
    o.x = LOG2E*(acc20-h)+qa; o.y = LOG2E*(acc21-h)+qb; o.z = LOG2E*(acc22-h)+qc; o.w = LOG2E*(acc23-h)+qd;
    *(float4*)&em2[row*CC + c0] = o;
  }
  {
    size_t row = row0 + r0 + 3; float h = 0.5f * x2a3; float4 o;
    o.x = LOG2E*(acc30-h)+qa; o.y = LOG2E*(acc31-h)+qb; o.z = LOG2E*(acc32-h)+qc; o.w = LOG2E*(acc33-h)+qd;
    *(float4*)&em2[row*CC + c0] = o;
  }
}

// ---------------------------------------------------------------------------
// Recursion, LINEAR domain with scaled-forward renorm. fp32 matvec only.
// Ring A[i] = 2^(beta_{t-1-i} + CE_t - CE_{t-1-i} - n_t), i=1..19.
//   a_t   = (v*rho)*W1 + rest           rest = sum_i A[i]*W[i+1]
//   v_t   = P . a_t                     (readlane matvec, fp32)
//   rho_{t+1} = 2^(em_{t+1} - kap - E)  (ONE exp2/step, off the serial chain)
// kap = wave_max(em_{t+1}) (prefetched 4 deep); E = clamped exponent of
// wave_max(v_{t-1}) (bit trick). n += kap + E; logZ = ln2*(n + log2 sum a).
// Clamps keep scale/Ef finite for ANY float input (algebra exact for any E).
// ---------------------------------------------------------------------------
__global__ __launch_bounds__(64, 1) void recur_kernel(
    const float* __restrict__ em2,
    const float* __restrict__ P_T,
    const float* __restrict__ init2,
    const float* __restrict__ len2,
    const int* __restrict__ lengths,
    float* __restrict__ out,
    int N) {
  int b = blockIdx.x;
  int c = threadIdx.x;  // channel

  float P[CC];
  #pragma unroll
  for (int j = 0; j < CC; ++j) P[j] = P_T[j * CC + c];
  float W[KK + 1];  // W[k] = 2^L_k, k=1..20
  #pragma unroll
  for (int k = 1; k <= KK; ++k) W[k] = EXP2(len2[(k - 1) * CC + c]);
  float W1 = W[1];

  const float* em_b = em2 + (size_t)b * N * CC;
  int len_b = lengths[b];

  float v = EXP2(init2[c]);     // v_0 = 2^init (n_0 = 0)
  float em1v = em_b[c];
  float q1 = em_b[(size_t)1 * CC + c];
  float q2v = em_b[(size_t)2 * CC + c];
  float q3 = em_b[(size_t)3 * CC + c];
  float q0 = em_b[(size_t)(4 <= N - 1 ? 4 : N - 1) * CC + c];
  float kap = wave_max64(em1v);
  float rho = EXP2(em1v - kap);  // rho_1
  float n = kap;                 // n_1
  float A[KK];
  #pragma unroll
  for (int i = 0; i < KK; ++i) A[i] = 0.f;
  float rest = 0.f;

  for (int t = 1; t <= N; ++t) {
    // ---- serial chain ----
    float A0 = v * rho;
    float a = fmaf(A0, W1, rest);

    if (t == len_b) {
      float s = wave_sum64(a);
      if (c == 0) out[b] = LN2 * (n + LOG2(s));
    }

    // ---- matvec v_new = P . a (fp32) ----
    float m0 = 0.f, m1 = 0.f, m2 = 0.f, m3 = 0.f;
    #pragma unroll
    for (int j = 0; j < CC; j += 4) {
      m0 = fmaf(P[j],     rlane(a, j),     m0);
      m1 = fmaf(P[j + 1], rlane(a, j + 1), m1);
      m2 = fmaf(P[j + 2], rlane(a, j + 2), m2);
      m3 = fmaf(P[j + 3], rlane(a, j + 3), m3);
    }
    float vnew = (m0 + m1) + (m2 + m3);

    // ---- off-chain prep for t+1 ----
    int rown = (t + 4 <= N - 1) ? (t + 4) : (N - 1);
    float emn;
    if ((t & 3) == 1)      { emn = q1;  q1  = em_b[(size_t)rown * CC + c]; }
    else if ((t & 3) == 2) { emn = q2v; q2v = em_b[(size_t)rown * CC + c]; }
    else if ((t & 3) == 3) { emn = q3;  q3  = em_b[(size_t)rown * CC + c]; }
    else                   { emn = q0;  q0  = em_b[(size_t)rown * CC + c]; }
    float kapn = wave_max64(emn);
    float rhot = EXP2(emn - kapn);
    float vmax = wave_max64(v);                      // v_{t-1} magnitude
    vmax = fminf(fmaxf(vmax, 1e-20f), 1e20f);        // keep eb in safe range
    int eb = (__float_as_int(vmax) >> 23) & 255;     // eb in [~60, ~193]
    float scale = __int_as_float((254 - eb) << 23);  // 2^-E, always finite
    float Ef = (float)(eb - 127);
    float rhon = rhot * scale;
    n = n + kapn + Ef;                               // n_{t+1}

    // ---- ring shift * rho_{t+1}, rest_{t+1} = sum A[i]*W[i+1] ----
    #pragma unroll
    for (int i = KK - 1; i >= 2; --i) A[i] = A[i - 1] * rhon;
    A[1] = A0 * rhon;
    float r0a = 0.f, r1a = 0.f, r2a = 0.f, r3a = 0.f;
    #pragma unroll
    for (int i = 1; i + 3 <= KK - 1; i += 4) {
      r0a = fmaf(A[i],     W[i + 1], r0a);
      r1a = fmaf(A[i + 1], W[i + 2], r1a);
      r2a = fmaf(A[i + 2], W[i + 3], r2a);
      r3a = fmaf(A[i + 3], W[i + 4], r3a);
    }
    r0a = fmaf(A[17], W[18], r0a);
    r1a = fmaf(A[18], W[19], r1a);
    r2a = fmaf(A[19], W[20], r2a);
    rest = (r0a + r1a) + (r2a + r3a);

    v = vnew;
    rho = rhon;
  }
}

extern "C" void kernel_launch(void* const* d_in, const int* in_sizes, int n_in,
                              void* d_out, int out_size, void* d_ws, size_t ws_size,
                              hipStream_t stream) {
  const float* feat   = (const float*)d_in[0];
  const int*   lens   = (const int*)d_in[1];
  const float* means  = (const float*)d_in[2];
  const float* cov    = (const float*)d_in[3];
  const float* tl     = (const float*)d_in[4];
  const float* il     = (const float*)d_in[5];
  const float* plr    = (const float*)d_in[6];
  int B = in_sizes[1];
  int D = in_sizes[2] / CC;
  int N = in_sizes[0] / (B * D);

  float* ws = (float*)d_ws;
  size_t off = 0;
  float* wmat   = ws + off; off += (size_t)CC * D;
  float* invvar = ws + off; off += D;
  float* q2     = ws + off; off += CC;
  float* P_T    = ws + off; off += CC * CC;
  float* init2  = ws + off; off += CC;
  float* len2   = ws + off; off += KK * CC;
  float* em2    = ws + off; off += (size_t)B * N * CC;

  hipLaunchKernelGGL(setup_kernel, dim3(1), dim3(256), 0, stream,
                     means, cov, tl, il, plr, wmat, invvar, q2, P_T, init2, len2, D);
  hipLaunchKernelGGL(emission_kernel, dim3((B * N) / 64), dim3(256), 0, stream,
                     feat, wmat, invvar, q2, em2, D);
  hipLaunchKernelGGL(recur_kernel, dim3(B), dim3(64), 0, stream,
                     em2, P_T, init2, len2, lens, (float*)d_out, N);
}

// Round 6
// 599.468 us; speedup vs baseline: 1.4474x; 1.4474x over previous
//
#include <hip/hip_runtime.h>
#include <math.h>

#define CC 64
#define KK 20
#define DCH 32
#define LOG2E 1.4426950408889634f
#define LN2   0.6931471805599453f
#define LN2PI 1.8378770664093453f
#define BIGN  -1.0e9f

#if __has_builtin(__builtin_amdgcn_exp2f)
#define EXP2(x) __builtin_amdgcn_exp2f(x)
#else
#define EXP2(x) exp2f(x)
#endif
#if __has_builtin(__builtin_amdgcn_logf)
#define LOG2(x) __builtin_amdgcn_logf(x)
#else
#define LOG2(x) log2f(x)
#endif

__device__ __forceinline__ float rlane(float v, int l) {
  return __int_as_float(__builtin_amdgcn_readlane(__float_as_int(v), l));
}

template <int Ctrl, int OldBits>
__device__ __forceinline__ float dpp_mov(float x) {
  return __int_as_float(__builtin_amdgcn_update_dpp(
      OldBits, __float_as_int(x), Ctrl, 0xf, 0xf, false));
}

__device__ __forceinline__ float wave_max64(float x) {
  constexpr int NI = (int)0xff800000;  // -inf
  x = fmaxf(x, dpp_mov<0x111, NI>(x));
  x = fmaxf(x, dpp_mov<0x112, NI>(x));
  x = fmaxf(x, dpp_mov<0x114, NI>(x));
  x = fmaxf(x, dpp_mov<0x118, NI>(x));
  x = fmaxf(x, dpp_mov<0x142, NI>(x));
  x = fmaxf(x, dpp_mov<0x143, NI>(x));
  return __int_as_float(__builtin_amdgcn_readlane(__float_as_int(x), 63));
}

__device__ __forceinline__ float wave_sum64(float x) {
  x += dpp_mov<0x111, 0>(x);
  x += dpp_mov<0x112, 0>(x);
  x += dpp_mov<0x114, 0>(x);
  x += dpp_mov<0x118, 0>(x);
  x += dpp_mov<0x142, 0>(x);
  x += dpp_mov<0x143, 0>(x);
  return __int_as_float(__builtin_amdgcn_readlane(__float_as_int(x), 63));
}

// ---------------------------------------------------------------------------
// Setup (R3-proven, unchanged)
// ---------------------------------------------------------------------------
__global__ void setup_kernel(const float* __restrict__ means,
                             const float* __restrict__ cov,
                             const float* __restrict__ tl,
                             const float* __restrict__ il,
                             const float* __restrict__ plr,
                             float* __restrict__ wmat,
                             float* __restrict__ invvar,
                             float* __restrict__ q2,
                             float* __restrict__ P_T,
                             float* __restrict__ init2,
                             float* __restrict__ len2,
                             int D) {
  __shared__ float red[256];
  int tid = threadIdx.x;
  for (int d = tid; d < D; d += 256) invvar[d] = 1.0f / cov[(size_t)d * D + d];
  float lp_ = 0.f;
  for (int d = tid; d < D; d += 256) lp_ += logf(cov[(size_t)d * D + d]);
  red[tid] = lp_;
  __syncthreads();
  for (int s = 128; s > 0; s >>= 1) {
    if (tid < s) red[tid] += red[tid + s];
    __syncthreads();
  }
  float logdet = red[0];
  __syncthreads();
  {
    int c = tid & 63, q = tid >> 6;
    int dq = D / 4;
    float m2p = 0.f;
    for (int d = q * dq; d < (q + 1) * dq; ++d) {
      float mu = means[c * D + d];
      m2p = fmaf(mu * mu, invvar[d], m2p);
    }
    red[tid] = m2p;
  }
  __syncthreads();
  for (int i = tid; i < CC * D; i += 256) wmat[i] = means[i] * invvar[i % D];
  if (tid < CC) {
    int c = tid;
    float m2 = red[c] + red[c + 64] + red[c + 128] + red[c + 192];
    q2[c] = -0.5f * LOG2E * (m2 + logdet + (float)D * LN2PI);
    int j = c;
    float mx = -1e30f;
    for (int i2 = 0; i2 < CC; ++i2) {
      float v = (i2 == j) ? BIGN : tl[i2 * CC + j];
      mx = fmaxf(mx, v);
    }
    float s = 0.f;
    for (int i2 = 0; i2 < CC; ++i2) {
      float v = (i2 == j) ? BIGN : tl[i2 * CC + j];
      s += expf(v - mx);
    }
    float inv = 1.f / s;
    for (int i2 = 0; i2 < CC; ++i2) {
      float v = (i2 == j) ? BIGN : tl[i2 * CC + j];
      P_T[j * CC + i2] = expf(v - mx) * inv;
    }
    float mi = -1e30f;
    for (int i2 = 0; i2 < CC; ++i2) mi = fmaxf(mi, il[i2]);
    float si = 0.f;
    for (int i2 = 0; i2 < CC; ++i2) si += expf(il[i2] - mi);
    init2[c] = LOG2E * (il[c] - (mi + logf(si)));
  }
  for (int i = tid; i < KK * CC; i += 256) {
    int k = i / CC, c = i % CC;
    float lr = plr[c];
    float lp = (float)(k + 1) * lr - expf(lr) - lgammaf((float)(k + 2));
    len2[i] = LOG2E * lp;
  }
}

// ---------------------------------------------------------------------------
// Emission: computes em (base-2), per-row kap = max_c em, stores
// emhat[row][c] = 2^(em - kap) and kmax[row] = kap.
// ---------------------------------------------------------------------------
__global__ __launch_bounds__(256) void emission_kernel(
    const float* __restrict__ feat,
    const float* __restrict__ wmat,
    const float* __restrict__ invvar,
    const float* __restrict__ q2,
    float* __restrict__ emhat,
    float* __restrict__ kmax,
    int D) {
  __shared__ float xs[64][DCH + 1];
  __shared__ float wsh[64][DCH + 1];
  __shared__ float ivv[DCH];
  __shared__ float q2s[CC];
  __shared__ float rmx[64][17];
  __shared__ float kapsh[64];
  int tid = threadIdx.x;
  size_t row0 = (size_t)blockIdx.x * 64;
  if (tid < CC) q2s[tid] = q2[tid];
  int tx = tid & 15, ty = tid >> 4;
  int r0 = ty * 4, c0 = tx * 4;
  int lr_ = tid >> 2;
  int lj  = (tid & 3) * 8;
  float acc00=0,acc01=0,acc02=0,acc03=0;
  float acc10=0,acc11=0,acc12=0,acc13=0;
  float acc20=0,acc21=0,acc22=0,acc23=0;
  float acc30=0,acc31=0,acc32=0,acc33=0;
  float x2a0=0,x2a1=0,x2a2=0,x2a3=0;
  for (int d0 = 0; d0 < D; d0 += DCH) {
    __syncthreads();
    {
      const float4* fx = (const float4*)(feat + (row0 + (size_t)lr_) * D + d0 + lj);
      float4 a = fx[0], b = fx[1];
      xs[lr_][lj+0]=a.x; xs[lr_][lj+1]=a.y; xs[lr_][lj+2]=a.z; xs[lr_][lj+3]=a.w;
      xs[lr_][lj+4]=b.x; xs[lr_][lj+5]=b.y; xs[lr_][lj+6]=b.z; xs[lr_][lj+7]=b.w;
      const float4* fw = (const float4*)(wmat + (size_t)lr_ * D + d0 + lj);
      float4 aw = fw[0], bw = fw[1];
      wsh[lr_][lj+0]=aw.x; wsh[lr_][lj+1]=aw.y; wsh[lr_][lj+2]=aw.z; wsh[lr_][lj+3]=aw.w;
      wsh[lr_][lj+4]=bw.x; wsh[lr_][lj+5]=bw.y; wsh[lr_][lj+6]=bw.z; wsh[lr_][lj+7]=bw.w;
      if (tid < DCH) ivv[tid] = invvar[d0 + tid];
    }
    __syncthreads();
    #pragma unroll
    for (int j = 0; j < DCH; ++j) {
      float iv = ivv[j];
      float xv0 = xs[r0+0][j], xv1 = xs[r0+1][j], xv2 = xs[r0+2][j], xv3 = xs[r0+3][j];
      float wv0 = wsh[c0+0][j], wv1 = wsh[c0+1][j], wv2 = wsh[c0+2][j], wv3 = wsh[c0+3][j];
      x2a0 = fmaf(xv0, xv0*iv, x2a0);
      x2a1 = fmaf(xv1, xv1*iv, x2a1);
      x2a2 = fmaf(xv2, xv2*iv, x2a2);
      x2a3 = fmaf(xv3, xv3*iv, x2a3);
      acc00 = fmaf(xv0, wv0, acc00); acc01 = fmaf(xv0, wv1, acc01);
      acc02 = fmaf(xv0, wv2, acc02); acc03 = fmaf(xv0, wv3, acc03);
      acc10 = fmaf(xv1, wv0, acc10); acc11 = fmaf(xv1, wv1, acc11);
      acc12 = fmaf(xv1, wv2, acc12); acc13 = fmaf(xv1, wv3, acc13);
      acc20 = fmaf(xv2, wv0, acc20); acc21 = fmaf(xv2, wv1, acc21);
      acc22 = fmaf(xv2, wv2, acc22); acc23 = fmaf(xv2, wv3, acc23);
      acc30 = fmaf(xv3, wv0, acc30); acc31 = fmaf(xv3, wv1, acc31);
      acc32 = fmaf(xv3, wv2, acc32); acc33 = fmaf(xv3, wv3, acc33);
    }
  }
  float qa = q2s[c0+0], qb = q2s[c0+1], qc = q2s[c0+2], qd = q2s[c0+3];
  float e0x, e0y, e0z, e0w, e1x, e1y, e1z, e1w;
  float e2x, e2y, e2z, e2w, e3x, e3y, e3z, e3w;
  {
    float h = 0.5f * x2a0;
    e0x = LOG2E*(acc00-h)+qa; e0y = LOG2E*(acc01-h)+qb;
    e0z = LOG2E*(acc02-h)+qc; e0w = LOG2E*(acc03-h)+qd;
  }
  {
    float h = 0.5f * x2a1;
    e1x = LOG2E*(acc10-h)+qa; e1y = LOG2E*(acc11-h)+qb;
    e1z = LOG2E*(acc12-h)+qc; e1w = LOG2E*(acc13-h)+qd;
  }
  {
    float h = 0.5f * x2a2;
    e2x = LOG2E*(acc20-h)+qa; e2y = LOG2E*(acc21-h)+qb;
    e2z = LOG2E*(acc22-h)+qc; e2w = LOG2E*(acc23-h)+qd;
  }
  {
    float h = 0.5f * x2a3;
    e3x = LOG2E*(acc30-h)+qa; e3y = LOG2E*(acc31-h)+qb;
    e3z = LOG2E*(acc32-h)+qc; e3w = LOG2E*(acc33-h)+qd;
  }
  // per-row max over this thread's 4 cols, then block reduce over tx
  rmx[r0 + 0][tx] = fmaxf(fmaxf(e0x, e0y), fmaxf(e0z, e0w));
  rmx[r0 + 1][tx] = fmaxf(fmaxf(e1x, e1y), fmaxf(e1z, e1w));
  rmx[r0 + 2][tx] = fmaxf(fmaxf(e2x, e2y), fmaxf(e2z, e2w));
  rmx[r0 + 3][tx] = fmaxf(fmaxf(e3x, e3y), fmaxf(e3z, e3w));
  __syncthreads();
  if (tid < 64) {
    float m = rmx[tid][0];
    #pragma unroll
    for (int j = 1; j < 16; ++j) m = fmaxf(m, rmx[tid][j]);
    kapsh[tid] = m;
    kmax[row0 + tid] = m;
  }
  __syncthreads();
  {
    float kp = kapsh[r0 + 0]; size_t row = row0 + r0 + 0; float4 o;
    o.x = EXP2(e0x - kp); o.y = EXP2(e0y - kp); o.z = EXP2(e0z - kp); o.w = EXP2(e0w - kp);
    *(float4*)&emhat[row * CC + c0] = o;
  }
  {
    float kp = kapsh[r0 + 1]; size_t row = row0 + r0 + 1; float4 o;
    o.x = EXP2(e1x - kp); o.y = EXP2(e1y - kp); o.z = EXP2(e1z - kp); o.w = EXP2(e1w - kp);
    *(float4*)&emhat[row * CC + c0] = o;
  }
  {
    float kp = kapsh[r0 + 2]; size_t row = row0 + r0 + 2; float4 o;
    o.x = EXP2(e2x - kp); o.y = EXP2(e2y - kp); o.z = EXP2(e2z - kp); o.w = EXP2(e2w - kp);
    *(float4*)&emhat[row * CC + c0] = o;
  }
  {
    float kp = kapsh[r0 + 3]; size_t row = row0 + r0 + 3; float4 o;
    o.x = EXP2(e3x - kp); o.y = EXP2(e3y - kp); o.z = EXP2(e3z - kp); o.w = EXP2(e3w - kp);
    *(float4*)&emhat[row * CC + c0] = o;
  }
}

// ---------------------------------------------------------------------------
// Recursion, linear domain, branchless unroll-4, no transcendental in loop.
//   a_t = (v*rho)*W1 + rest;  v_t = P.a_t (fp32 readlane matvec)
//   rhon = emhat_{t+1} * 2^-E  (E = exponent of wave_max(v_{t-1}), bit trick)
//   rest' = rhon * S2,  S2 = A0*W2 + sum_{i=1..18} A[i]*W[i+2]  (old ring)
// Normalizer: logZ = ln2*(Skap(len) + EfSum + log2(sum a)); Skap from kmax[].
// ---------------------------------------------------------------------------
__global__ __launch_bounds__(64, 1) void recur_kernel(
    const float* __restrict__ emhat,
    const float* __restrict__ kmax,
    const float* __restrict__ P_T,
    const float* __restrict__ init2,
    const float* __restrict__ len2,
    const int* __restrict__ lengths,
    float* __restrict__ out,
    int N) {
  int b = blockIdx.x;
  int c = threadIdx.x;

  float P[CC];
  #pragma unroll
  for (int j = 0; j < CC; ++j) P[j] = P_T[j * CC + c];
  float W[KK + 1];
  #pragma unroll
  for (int k = 1; k <= KK; ++k) W[k] = EXP2(len2[(k - 1) * CC + c]);
  float W1 = W[1];

  const float* eh_b = emhat + (size_t)b * N * CC;
  const float* km_b = kmax + (size_t)b * N;
  int len_b = lengths[b];

  // Skap = sum of kap over rows 0..len_b-1
  float skp = 0.f;
  for (int r = c; r < len_b; r += 64) skp += km_b[r];
  float Skap = wave_sum64(skp);

  float v = EXP2(init2[c]);
  float rho = eh_b[c];  // row 0
  float q0v = eh_b[(size_t)(1 <= N - 1 ? 1 : N - 1) * CC + c];
  float q1v = eh_b[(size_t)(2 <= N - 1 ? 2 : N - 1) * CC + c];
  float q2v = eh_b[(size_t)(3 <= N - 1 ? 3 : N - 1) * CC + c];
  float q3v = eh_b[(size_t)(4 <= N - 1 ? 4 : N - 1) * CC + c];
  float EfSum = 0.f;
  float A[KK];
  #pragma unroll
  for (int i = 0; i < KK; ++i) A[i] = 0.f;
  float rest = 0.f;

  auto body = [&](int t, float& q) {
    // ---- serial chain head ----
    float A0 = v * rho;
    float a = fmaf(A0, W1, rest);

    if (t == len_b) {
      float s_ = wave_sum64(a);
      if (c == 0) out[b] = LN2 * (Skap + EfSum + LOG2(s_));
    }

    // ---- S2 from OLD ring (overlaps matvec) ----
    float u0 = A0 * W[2], u1 = 0.f, u2 = 0.f, u3 = 0.f;
    #pragma unroll
    for (int i = 1; i + 3 <= 16; i += 4) {
      u0 = fmaf(A[i],     W[i + 2], u0);
      u1 = fmaf(A[i + 1], W[i + 3], u1);
      u2 = fmaf(A[i + 2], W[i + 4], u2);
      u3 = fmaf(A[i + 3], W[i + 5], u3);
    }
    u1 = fmaf(A[17], W[19], u1);
    u2 = fmaf(A[18], W[20], u2);
    float S2 = (u0 + u1) + (u2 + u3);

    // ---- matvec v_new = P . a ----
    float m0 = 0.f, m1 = 0.f, m2 = 0.f, m3 = 0.f;
    #pragma unroll
    for (int j = 0; j < CC; j += 4) {
      m0 = fmaf(P[j],     rlane(a, j),     m0);
      m1 = fmaf(P[j + 1], rlane(a, j + 1), m1);
      m2 = fmaf(P[j + 2], rlane(a, j + 2), m2);
      m3 = fmaf(P[j + 3], rlane(a, j + 3), m3);
    }
    float vnew = (m0 + m1) + (m2 + m3);

    // ---- prefetch rotation (straight-line; reload for t+4) ----
    float rh = q;
    int rown = (t + 4 <= N - 1) ? (t + 4) : (N - 1);
    q = eh_b[(size_t)rown * CC + c];

    // ---- renorm (uses OLD v; overlaps everything) ----
    float vmax = wave_max64(v);
    vmax = fminf(fmaxf(vmax, 1e-20f), 1e20f);
    int eb = (__float_as_int(vmax) >> 23) & 255;
    float scale = __int_as_float((254 - eb) << 23);
    EfSum += (float)(eb - 127);
    float rhon = rh * scale;
    rest = rhon * S2;

    // ---- ring shift (for next step's S2) ----
    #pragma unroll
    for (int i = KK - 1; i >= 2; --i) A[i] = A[i - 1] * rhon;
    A[1] = A0 * rhon;

    v = vnew;
    rho = rhon;
  };

  int t = 1;
  for (; t + 3 <= N; t += 4) {
    body(t,     q0v);
    body(t + 1, q1v);
    body(t + 2, q2v);
    body(t + 3, q3v);
  }
  for (; t <= N; ++t) {
    int s = t & 3;
    if (s == 1)      body(t, q0v);
    else if (s == 2) body(t, q1v);
    else if (s == 3) body(t, q2v);
    else             body(t, q3v);
  }
}

extern "C" void kernel_launch(void* const* d_in, const int* in_sizes, int n_in,
                              void* d_out, int out_size, void* d_ws, size_t ws_size,
                              hipStream_t stream) {
  const float* feat   = (const float*)d_in[0];
  const int*   lens   = (const int*)d_in[1];
  const float* means  = (const float*)d_in[2];
  const float* cov    = (const float*)d_in[3];
  const float* tl     = (const float*)d_in[4];
  const float* il     = (const float*)d_in[5];
  const float* plr    = (const float*)d_in[6];
  int B = in_sizes[1];
  int D = in_sizes[2] / CC;
  int N = in_sizes[0] / (B * D);

  float* ws = (float*)d_ws;
  size_t off = 0;
  float* wmat   = ws + off; off += (size_t)CC * D;
  float* invvar = ws + off; off += D;
  float* q2     = ws + off; off += CC;
  float* P_T    = ws + off; off += CC * CC;
  float* init2  = ws + off; off += CC;
  float* len2   = ws + off; off += KK * CC;
  float* emhat  = ws + off; off += (size_t)B * N * CC;
  float* kmax   = ws + off; off += (size_t)B * N;

  hipLaunchKernelGGL(setup_kernel, dim3(1), dim3(256), 0, stream,
                     means, cov, tl, il, plr, wmat, invvar, q2, P_T, init2, len2, D);
  hipLaunchKernelGGL(emission_kernel, dim3((B * N) / 64), dim3(256), 0, stream,
                     feat, wmat, invvar, q2, emhat, kmax, D);
  hipLaunchKernelGGL(recur_kernel, dim3(B), dim3(64), 0, stream,
                     emhat, kmax, P_T, init2, len2, lens, (float*)d_out, N);
}